// Round 6
// baseline (257.994 us; speedup 1.0000x reference)
//
#include <hip/hip_runtime.h>

#define B_   2
#define CIN  16
#define HIN  384
#define WIN  1280
#define CO   24
#define HQ   96
#define WL   320
#define WR   1280
#define DMAX 64

__device__ __forceinline__ float lk(float v) { return v >= 0.f ? v : 0.2f * v; }

// ============ Kernel A: em_left (4x4 s4,4 VALID) + leaky + rc 1x1 + leaky ====
// block 256 = 128 px * 2 o-halves (12 out-ch each); grid 480.  [R5 version]
__global__ __launch_bounds__(256) void k_left(
    const float* __restrict__ x, const float* __restrict__ w_em,
    const float* __restrict__ b_em, const float* __restrict__ w_rc,
    const float* __restrict__ b_rc, float* __restrict__ out)
{
    __shared__ float smem[CO * CIN * 16];  // em weights during conv, then em acts
    __shared__ __align__(16) float swt[CO * CO];   // rc weights transposed [c][o]
    __shared__ float sbe[CO], sbr[CO];

    for (int i = threadIdx.x; i < CO * CIN * 16; i += 256) smem[i] = w_em[i];
    for (int i = threadIdx.x; i < CO * CO; i += 256) swt[i] = w_rc[(i % CO) * CO + (i / CO)];
    if (threadIdx.x < CO) { sbe[threadIdx.x] = b_em[threadIdx.x]; sbr[threadIdx.x] = b_rc[threadIdx.x]; }
    __syncthreads();

    const int t = threadIdx.x;
    const int half = t >> 7, pxl = t & 127;
    const int obase = half * 12;
    const int flat = blockIdx.x * 128 + pxl;       // < 61440
    const int j = flat % WL, h = (flat / WL) % HQ, b = flat / (WL * HQ);

    float acc[12];
#pragma unroll
    for (int oo = 0; oo < 12; ++oo) acc[oo] = sbe[obase + oo];

    for (int c = 0; c < CIN; ++c) {
#pragma unroll
        for (int kh = 0; kh < 4; ++kh) {
            const float4 v = *(const float4*)(x + ((size_t)(b * CIN + c) * HIN + 4 * h + kh) * WIN + 4 * j);
#pragma unroll
            for (int oo = 0; oo < 12; ++oo) {
                const float4 wv = *(const float4*)&smem[(((obase + oo) * CIN + c) * 4 + kh) * 4];
                float a = acc[oo];
                a = fmaf(v.x, wv.x, a);
                a = fmaf(v.y, wv.y, a);
                a = fmaf(v.z, wv.z, a);
                a = fmaf(v.w, wv.w, a);
                acc[oo] = a;
            }
        }
    }
    __syncthreads();
#pragma unroll
    for (int oo = 0; oo < 12; ++oo) smem[(obase + oo) * 128 + pxl] = lk(acc[oo]);
    __syncthreads();

    float acc2[12];
#pragma unroll
    for (int oo = 0; oo < 12; ++oo) acc2[oo] = sbr[obase + oo];
    for (int c = 0; c < CO; ++c) {
        const float in_c = smem[c * 128 + pxl];
#pragma unroll
        for (int m = 0; m < 3; ++m) {
            const float4 wv = *(const float4*)&swt[c * CO + obase + 4 * m];   // 16B aligned
            acc2[4 * m + 0] = fmaf(in_c, wv.x, acc2[4 * m + 0]);
            acc2[4 * m + 1] = fmaf(in_c, wv.y, acc2[4 * m + 1]);
            acc2[4 * m + 2] = fmaf(in_c, wv.z, acc2[4 * m + 2]);
            acc2[4 * m + 3] = fmaf(in_c, wv.w, acc2[4 * m + 3]);
        }
    }
#pragma unroll
    for (int oo = 0; oo < 12; ++oo)
        out[((size_t)(b * CO + obase + oo) * HQ + h) * WL + j] = lk(acc2[oo]);
}

// ======= Kernel B: em_right (4x4 s4,1 pad 1,2) + leaky + rc 1x1 + leaky ======
// R6: ROW-PAIRED on the lean R5 base. R5 counters: VALUBusy 43% + computed
// LDS-pipe busy 43% = 86% combined -> instruction-mix-bound, not overlap.
// Each thread computes its 4-col group for TWO rows (h, h+48): each conv
// weight ds_read_b128 serves 32 fmaf (was 16), each rc swt float4 serves 8
// (was 4) -> LDS demand halves (~31 -> ~15us chip-wide), mix goes VALU-bound.
// R4's version of this spilled (VGPR 256, WRITE 107MB) because it sat on the
// VGPR-160 pipelined base with no cap; here base is VGPR 60 and
// __launch_bounds__(256,2) forces <=128. Math = exact R5 fmaf chains ->
// bitwise identical. Grid 480 = 2b x 48hp x 5tiles; acts [24][2][256]
// unioned with weights (49.2KB LDS). WATCH: WRITE_SIZE must stay 23040.
__global__ __launch_bounds__(256, 2) void k_right(
    const float* __restrict__ x, const float* __restrict__ w_em,
    const float* __restrict__ b_em, const float* __restrict__ w_rc,
    const float* __restrict__ b_rc, float* __restrict__ out)
{
    __shared__ __align__(16) float buf[CO * 512];  // weights (6144 fl), then acts [24][2][256]
    __shared__ __align__(16) float swt[CO * CO];
    __shared__ float sbe[CO], sbr[CO];

    for (int i = threadIdx.x; i < CO * CIN * 16; i += 256) buf[i] = w_em[i];
    for (int i = threadIdx.x; i < CO * CO; i += 256) swt[i] = w_rc[(i % CO) * CO + (i / CO)];
    if (threadIdx.x < CO) { sbe[threadIdx.x] = b_em[threadIdx.x]; sbr[threadIdx.x] = b_rc[threadIdx.x]; }
    __syncthreads();

    const int t = threadIdx.x;
    const int L = t & 63, quarter = t >> 6;
    const int obase = quarter * 6;
    const int tile = blockIdx.x % 5;
    const int rest = blockIdx.x / 5;
    const int hp = rest % 48, b = rest / 48;
    const int jbase = tile * 256;

    // Edge handling (loop-invariant; same masks for both rows -- column logic).
    const bool vm1 = (jbase + 4 * L) > 0;
    const bool vp  = (jbase + 4 * L + 4) < WIN;
    const int  om1 = vm1 ? (4 * L - 2) : 0;
    const int  op4 = vp  ? (4 * L + 4) : 0;
    const int  L4  = 4 * L;
    const size_t cstride = (size_t)HIN * WIN;
    const size_t rowstride = (size_t)4 * 48 * WIN;   // h -> h+48

    const float* xc0 = x + ((size_t)(b * CIN) * HIN + 4 * hp) * WIN + jbase;

    float acc[2][4][6];
#pragma unroll
    for (int oo = 0; oo < 6; ++oo) {
        const float be = sbe[obase + oo];
#pragma unroll
        for (int k = 0; k < 4; ++k) { acc[0][k][oo] = be; acc[1][k][oo] = be; }
    }

#pragma unroll 1
    for (int c = 0; c < CIN; ++c) {
        const float* r0 = xc0 + c * cstride;
#pragma unroll
        for (int kh = 0; kh < 4; ++kh) {
            const float* p0 = r0 + kh * WIN;
            const float* p1 = p0 + rowstride;
            const float4 v0 = *(const float4*)(p0 + L4);
            const float2 A0 = *(const float2*)(p0 + om1);
            const float2 C0 = *(const float2*)(p0 + op4);
            const float4 v1 = *(const float4*)(p1 + L4);
            const float2 A1 = *(const float2*)(p1 + om1);
            const float2 C1 = *(const float2*)(p1 + op4);
            float in0[7], in1[7];
            in0[0] = vm1 ? A0.y : 0.f;
            in0[1] = v0.x; in0[2] = v0.y; in0[3] = v0.z; in0[4] = v0.w;
            in0[5] = vp ? C0.x : 0.f;
            in0[6] = vp ? C0.y : 0.f;
            in1[0] = vm1 ? A1.y : 0.f;
            in1[1] = v1.x; in1[2] = v1.y; in1[3] = v1.z; in1[4] = v1.w;
            in1[5] = vp ? C1.x : 0.f;
            in1[6] = vp ? C1.y : 0.f;
#pragma unroll
            for (int oo = 0; oo < 6; ++oo) {
                const float4 wv = *(const float4*)&buf[(((obase + oo) * CIN + c) * 4 + kh) * 4];
#pragma unroll
                for (int k = 0; k < 4; ++k) {
                    float a0 = acc[0][k][oo];
                    a0 = fmaf(in0[k],     wv.x, a0);
                    a0 = fmaf(in0[k + 1], wv.y, a0);
                    a0 = fmaf(in0[k + 2], wv.z, a0);
                    a0 = fmaf(in0[k + 3], wv.w, a0);
                    acc[0][k][oo] = a0;
                    float a1 = acc[1][k][oo];
                    a1 = fmaf(in1[k],     wv.x, a1);
                    a1 = fmaf(in1[k + 1], wv.y, a1);
                    a1 = fmaf(in1[k + 2], wv.z, a1);
                    a1 = fmaf(in1[k + 3], wv.w, a1);
                    acc[1][k][oo] = a1;
                }
            }
        }
    }
    __syncthreads();   // all waves done reading em weights; buf becomes act buffer
#pragma unroll
    for (int oo = 0; oo < 6; ++oo) {
        float4 s0 = make_float4(lk(acc[0][0][oo]), lk(acc[0][1][oo]), lk(acc[0][2][oo]), lk(acc[0][3][oo]));
        float4 s1 = make_float4(lk(acc[1][0][oo]), lk(acc[1][1][oo]), lk(acc[1][2][oo]), lk(acc[1][3][oo]));
        *(float4*)&buf[((obase + oo) * 2 + 0) * 256 + 4 * L] = s0;
        *(float4*)&buf[((obase + oo) * 2 + 1) * 256 + 4 * L] = s1;
    }
    __syncthreads();

    // rc 1x1: both rows share each swt float4 read (8 fmaf per read).
    float acc2[2][CO];
#pragma unroll
    for (int o = 0; o < CO; ++o) { acc2[0][o] = sbr[o]; acc2[1][o] = sbr[o]; }
#pragma unroll 1
    for (int c = 0; c < CO; ++c) {
        const float i0 = buf[(c * 2 + 0) * 256 + t];
        const float i1 = buf[(c * 2 + 1) * 256 + t];
#pragma unroll
        for (int m = 0; m < 6; ++m) {
            const float4 wv = *(const float4*)&swt[c * CO + 4 * m];   // 16B aligned
            acc2[0][4 * m + 0] = fmaf(i0, wv.x, acc2[0][4 * m + 0]);
            acc2[0][4 * m + 1] = fmaf(i0, wv.y, acc2[0][4 * m + 1]);
            acc2[0][4 * m + 2] = fmaf(i0, wv.z, acc2[0][4 * m + 2]);
            acc2[0][4 * m + 3] = fmaf(i0, wv.w, acc2[0][4 * m + 3]);
            acc2[1][4 * m + 0] = fmaf(i1, wv.x, acc2[1][4 * m + 0]);
            acc2[1][4 * m + 1] = fmaf(i1, wv.y, acc2[1][4 * m + 1]);
            acc2[1][4 * m + 2] = fmaf(i1, wv.z, acc2[1][4 * m + 2]);
            acc2[1][4 * m + 3] = fmaf(i1, wv.w, acc2[1][4 * m + 3]);
        }
    }
#pragma unroll
    for (int o = 0; o < CO; ++o) {
        out[((size_t)(b * CO + o) * HQ + hp) * WR + jbase + t]        = lk(acc2[0][o]);
        out[((size_t)(b * CO + o) * HQ + hp + 48) * WR + jbase + t]   = lk(acc2[1][o]);
    }
}

// ====== Kernel C: cost volume + min/argmin + tf 1x1 + output assembly ========
// block 256 = 64 j-lanes x 4 waves (wave w owns d in [16w,16w+16)); grid 960.
// LDS layout: frs[c*324 + 2 + (col - colbase)], colbase = 4*j0-64; cols<0
// replicated with fr[c][0] (reference's lower clip; upper clip never fires).
// The +2 shift makes each (c, d-quad) gather group of 4 consecutive cols
// 16B-aligned -> one ds_read_b128 replaces 4 ds_read_b32. Channel-ascending
// += of fabsf keeps costs bitwise-identical -> argmin tie behavior preserved.
__global__ __launch_bounds__(256) void k_cost(
    const float* __restrict__ fl, const float* __restrict__ fr,
    const float* __restrict__ wtf, const float* __restrict__ btf,
    float* __restrict__ out, float* __restrict__ cost)
{
    __shared__ float frs[CO * 324];       // 31104 B
    __shared__ float sbest[256];
    __shared__ int   sbd[256];

    const int t  = threadIdx.x;
    const int j  = t & 63;                 // lane = local col
    const int w  = t >> 6;                 // wave: d in [16w, 16w+16)
    const int jc = blockIdx.x % 5;
    const int r  = blockIdx.x / 5;
    const int h  = r % HQ, b = r / HQ;
    const int j0 = jc * 64;
    const int jg = j0 + j;
    const int colbase = 4 * j0 - 64;

    // stage 24 rows x 320 cols (coalesced; left-clip replication)
    for (int idx = t; idx < CO * 320; idx += 256) {
        const int c = idx / 320, Wd = idx % 320;
        const int col = colbase + Wd;
        frs[c * 324 + 2 + Wd] = fr[((size_t)(b * CO + c) * HQ + h) * WR + (col > 0 ? col : 0)];
    }
    __syncthreads();

    float acc[4][4];                       // [q][r], d = 16w + 4q + r
#pragma unroll
    for (int q = 0; q < 4; ++q)
#pragma unroll
        for (int rr = 0; rr < 4; ++rr) acc[q][rr] = 0.f;

    for (int c = 0; c < CO; ++c) {
        const float flc = fl[((size_t)(b * CO + c) * HQ + h) * WL + jg];
        const float* base = &frs[c * 324 + 4 * j + 64];
#pragma unroll
        for (int q = 0; q < 4; ++q) {
            const int D = 4 * w + q;
            const float4 v = *(const float4*)(base - 4 * D);  // 16B-aligned
            acc[q][0] += fabsf(flc - v.w);   // d = 4D
            acc[q][1] += fabsf(flc - v.z);   // d = 4D+1
            acc[q][2] += fabsf(flc - v.y);   // d = 4D+2
            acc[q][3] += fabsf(flc - v.x);   // d = 4D+3
        }
    }

    // cost volume writes (coalesced over jg)
#pragma unroll
    for (int q = 0; q < 4; ++q)
#pragma unroll
        for (int rr = 0; rr < 4; ++rr) {
            const int d = 16 * w + 4 * q + rr;
            cost[((size_t)(b * DMAX + d) * HQ + h) * WL + jg] = acc[q][rr];
        }

    // per-thread min / first-occurrence argmin (ascending d within wave range)
    float best = acc[0][0]; int bd = 16 * w;
#pragma unroll
    for (int q = 0; q < 4; ++q)
#pragma unroll
        for (int rr = 0; rr < 4; ++rr) {
            if (q == 0 && rr == 0) continue;
            const int d = 16 * w + 4 * q + rr;
            if (acc[q][rr] < best) { best = acc[q][rr]; bd = d; }
        }
    sbest[t] = best; sbd[t] = bd;
    __syncthreads();

    if (t < 64) {
        float cur = sbest[j]; int curd = sbd[j];
#pragma unroll
        for (int g = 1; g < 4; ++g) {
            const float v = sbest[g * 64 + j];
            if (v < cur) { cur = v; curd = sbd[g * 64 + j]; }
        }
        float flr[CO];
#pragma unroll
        for (int c = 0; c < CO; ++c) flr[c] = fl[((size_t)(b * CO + c) * HQ + h) * WL + jg];
#pragma unroll
        for (int o = 0; o < 13; ++o) {
            float a = btf[o] + wtf[o * 25] * cur;
#pragma unroll
            for (int c = 0; c < CO; ++c) a += wtf[o * 25 + 1 + c] * flr[c];
            out[((size_t)(b * 16 + 3 + o) * HQ + h) * WL + jg] = lk(a);
        }
        out[((size_t)(b * 16 + 0) * HQ + h) * WL + jg] = (float)curd;
        out[((size_t)(b * 16 + 1) * HQ + h) * WL + jg] = 0.f;
        out[((size_t)(b * 16 + 2) * HQ + h) * WL + jg] = 0.f;
    }
}

extern "C" void kernel_launch(void* const* d_in, const int* in_sizes, int n_in,
                              void* d_out, int out_size, void* d_ws, size_t ws_size,
                              hipStream_t stream) {
    const float* fl_in = (const float*)d_in[0];
    const float* fr_in = (const float*)d_in[1];
    // d_in[2] = max_disp (int) -- fixed 64
    const float* w_em = (const float*)d_in[3];
    const float* b_em = (const float*)d_in[4];
    const float* w_rc = (const float*)d_in[5];
    const float* b_rc = (const float*)d_in[6];
    const float* w_tf = (const float*)d_in[7];
    const float* b_tf = (const float*)d_in[8];

    float* out  = (float*)d_out;
    float* cost = out + (size_t)B_ * 16 * HQ * WL;

    float* fl_ws = (float*)d_ws;                               // [2,24,96,320]
    float* fr_ws = fl_ws + (size_t)B_ * CO * HQ * WL;          // [2,24,96,1280]

    hipLaunchKernelGGL(k_right, dim3(480), dim3(256), 0, stream,
                       fr_in, w_em, b_em, w_rc, b_rc, fr_ws);
    hipLaunchKernelGGL(k_left,  dim3(480), dim3(256), 0, stream,
                       fl_in, w_em, b_em, w_rc, b_rc, fl_ws);
    hipLaunchKernelGGL(k_cost,  dim3(960), dim3(256), 0, stream,
                       fl_ws, fr_ws, w_tf, b_tf, out, cost);
}

// Round 7
// 237.728 us; speedup vs baseline: 1.0852x; 1.0852x over previous
//
#include <hip/hip_runtime.h>

#define B_   2
#define CIN  16
#define HIN  384
#define WIN  1280
#define CO   24
#define HQ   96
#define WL   320
#define WR   1280
#define DMAX 64

__device__ __forceinline__ float lk(float v) { return v >= 0.f ? v : 0.2f * v; }

// ============ Kernel A: em_left (4x4 s4,4 VALID) + leaky + rc 1x1 + leaky ====
// block 256 = 128 px * 2 o-halves (12 out-ch each); grid 480  [R0/R1 proven]
__global__ __launch_bounds__(256) void k_left(
    const float* __restrict__ x, const float* __restrict__ w_em,
    const float* __restrict__ b_em, const float* __restrict__ w_rc,
    const float* __restrict__ b_rc, float* __restrict__ out)
{
    __shared__ float smem[CO * CIN * 16];  // em weights during conv, then em acts
    __shared__ float swt[CO * CO];         // rc weights transposed [c][o]
    __shared__ float sbe[CO], sbr[CO];

    for (int i = threadIdx.x; i < CO * CIN * 16; i += 256) smem[i] = w_em[i];
    for (int i = threadIdx.x; i < CO * CO; i += 256) swt[i] = w_rc[(i % CO) * CO + (i / CO)];
    if (threadIdx.x < CO) { sbe[threadIdx.x] = b_em[threadIdx.x]; sbr[threadIdx.x] = b_rc[threadIdx.x]; }
    __syncthreads();

    const int t = threadIdx.x;
    const int half = t >> 7, pxl = t & 127;
    const int obase = half * 12;
    const int flat = blockIdx.x * 128 + pxl;       // < 61440
    const int j = flat % WL, h = (flat / WL) % HQ, b = flat / (WL * HQ);

    float acc[12];
#pragma unroll
    for (int oo = 0; oo < 12; ++oo) acc[oo] = sbe[obase + oo];

    for (int c = 0; c < CIN; ++c) {
#pragma unroll
        for (int kh = 0; kh < 4; ++kh) {
            const float4 v = *(const float4*)(x + ((size_t)(b * CIN + c) * HIN + 4 * h + kh) * WIN + 4 * j);
#pragma unroll
            for (int oo = 0; oo < 12; ++oo) {
                const float4 wv = *(const float4*)&smem[(((obase + oo) * CIN + c) * 4 + kh) * 4];
                acc[oo] += v.x * wv.x + v.y * wv.y + v.z * wv.z + v.w * wv.w;
            }
        }
    }
    __syncthreads();
#pragma unroll
    for (int oo = 0; oo < 12; ++oo) smem[(obase + oo) * 128 + pxl] = lk(acc[oo]);
    __syncthreads();

    float acc2[12];
#pragma unroll
    for (int oo = 0; oo < 12; ++oo) acc2[oo] = sbr[obase + oo];
    for (int c = 0; c < CO; ++c) {
        const float in_c = smem[c * 128 + pxl];
#pragma unroll
        for (int oo = 0; oo < 12; ++oo) acc2[oo] += in_c * swt[c * CO + obase + oo];
    }
#pragma unroll
    for (int oo = 0; oo < 12; ++oo)
        out[((size_t)(b * CO + obase + oo) * HQ + h) * WL + j] = lk(acc2[oo]);
}

// ======= Kernel B: em_right (4x4 s4,1 pad 1,2) + leaky + rc 1x1 + leaky ======
// R5 version EXACT (71us, VGPR 60, occ 31%): single row, 4 px/thread, LDS
// union 27136B, fmaf chains, float4 swt reads. R6's row-pairing regressed
// (TLP halved: 1920 vs 3840 waves chip-wide beats LDS-op halving).
__global__ __launch_bounds__(256) void k_right(
    const float* __restrict__ x, const float* __restrict__ w_em,
    const float* __restrict__ b_em, const float* __restrict__ w_rc,
    const float* __restrict__ b_rc, float* __restrict__ out)
{
    __shared__ __align__(16) float sw[CO * CIN * 16];  // weights, then em acts [24][256]
    __shared__ __align__(16) float swt[CO * CO];
    __shared__ float sbe[CO], sbr[CO];

    for (int i = threadIdx.x; i < CO * CIN * 16; i += 256) sw[i] = w_em[i];
    for (int i = threadIdx.x; i < CO * CO; i += 256) swt[i] = w_rc[(i % CO) * CO + (i / CO)];
    if (threadIdx.x < CO) { sbe[threadIdx.x] = b_em[threadIdx.x]; sbr[threadIdx.x] = b_rc[threadIdx.x]; }
    __syncthreads();

    const int t = threadIdx.x;
    const int L = t & 63, quarter = t >> 6;
    const int obase = quarter * 6;
    const int row = blockIdx.x / 5, jbase = (blockIdx.x % 5) * 256;
    const int b = row / HQ, h = row % HQ;

    const bool vm1 = (jbase + 4 * L) > 0;
    const bool vp  = (jbase + 4 * L + 4) < WIN;
    const int  om1 = vm1 ? (4 * L - 2) : 0;
    const int  op4 = vp  ? (4 * L + 4) : 0;

    float acc[4][6];
#pragma unroll
    for (int k = 0; k < 4; ++k)
#pragma unroll
        for (int oo = 0; oo < 6; ++oo) acc[k][oo] = sbe[obase + oo];

    for (int c = 0; c < CIN; ++c) {
#pragma unroll
        for (int kh = 0; kh < 4; ++kh) {
            const float* xr = x + ((size_t)(b * CIN + c) * HIN + 4 * h + kh) * WIN + jbase;
            const float4  v = *(const float4*)(xr + 4 * L);
            const float2  A = *(const float2*)(xr + om1);   // cols 4L-2, 4L-1
            const float2  C = *(const float2*)(xr + op4);   // cols 4L+4, 4L+5
            float in[7];
            in[0] = vm1 ? A.y : 0.f;
            in[1] = v.x; in[2] = v.y; in[3] = v.z; in[4] = v.w;
            in[5] = vp ? C.x : 0.f;
            in[6] = vp ? C.y : 0.f;
#pragma unroll
            for (int oo = 0; oo < 6; ++oo) {
                const float4 wv = *(const float4*)&sw[(((obase + oo) * CIN + c) * 4 + kh) * 4];
#pragma unroll
                for (int k = 0; k < 4; ++k) {
                    float a = acc[k][oo];
                    a = fmaf(in[k],     wv.x, a);
                    a = fmaf(in[k + 1], wv.y, a);
                    a = fmaf(in[k + 2], wv.z, a);
                    a = fmaf(in[k + 3], wv.w, a);
                    acc[k][oo] = a;
                }
            }
        }
    }
    __syncthreads();   // all waves done reading em weights; sw becomes act buffer
#pragma unroll
    for (int oo = 0; oo < 6; ++oo) {
        float4 st = make_float4(lk(acc[0][oo]), lk(acc[1][oo]), lk(acc[2][oo]), lk(acc[3][oo]));
        *(float4*)&sw[(obase + oo) * 256 + 4 * L] = st;
    }
    __syncthreads();

    float acc2[CO];
#pragma unroll
    for (int o = 0; o < CO; ++o) acc2[o] = sbr[o];
    for (int c = 0; c < CO; ++c) {
        const float in_c = sw[c * 256 + t];
#pragma unroll
        for (int m = 0; m < 6; ++m) {
            const float4 wv = *(const float4*)&swt[c * CO + 4 * m];   // 16B aligned
            acc2[4 * m + 0] = fmaf(in_c, wv.x, acc2[4 * m + 0]);
            acc2[4 * m + 1] = fmaf(in_c, wv.y, acc2[4 * m + 1]);
            acc2[4 * m + 2] = fmaf(in_c, wv.z, acc2[4 * m + 2]);
            acc2[4 * m + 3] = fmaf(in_c, wv.w, acc2[4 * m + 3]);
        }
    }
#pragma unroll
    for (int o = 0; o < CO; ++o)
        out[((size_t)(b * CO + o) * HQ + h) * WR + jbase + t] = lk(acc2[o]);
}

// ====== Kernel C: cost volume + min/argmin + tf 1x1 + output assembly ========
// R7: COL-PAIRED gather + parallel tail. Thread (p = t&31 col-pair,
// g = t>>5 d-octant) computes cols {2p,2p+1} x d in [8g,8g+8). The two cols'
// 8-float windows overlap by 4 -> 12 contiguous floats = 3 aligned
// ds_read_b128 serve 16 outputs (was 4 reads/16: -25% LDS-pipe ops on a
// ~3:1 LDS-bound loop). Element map: frs idx of (colLoc, d) = 4*colLoc+67-d;
// base = 8p-8g+60 (16B aligned; range [4,320) in [0,324) -- staged).
// E[I]=F[I/4].comp: colA d=8g+dd <- E[7-dd]; colB <- E[11-dd].
// Channel-ascending single += per c -> cost bitwise identical; per-thread
// argmin d-ascending then g-ascending reduction = global first-occurrence.
// Tail: tf 1x1 split across all 4 waves by output (was 1 wave doing 13 dots).
__global__ __launch_bounds__(256) void k_cost(
    const float* __restrict__ fl, const float* __restrict__ fr,
    const float* __restrict__ wtf, const float* __restrict__ btf,
    float* __restrict__ out, float* __restrict__ cost)
{
    __shared__ float frs[CO * 324];       // 31104 B
    __shared__ float sbest[8 * 64];       // [g][col]
    __shared__ int   sbd[8 * 64];

    const int t  = threadIdx.x;
    const int p  = t & 31;                 // col-pair
    const int g  = t >> 5;                 // d-octant: d in [8g, 8g+8)
    const int jc = blockIdx.x % 5;
    const int r  = blockIdx.x / 5;
    const int h  = r % HQ, b = r / HQ;
    const int j0 = jc * 64;
    const int colbase = 4 * j0 - 64;
    const int cA = 2 * p;                  // local cols cA, cA+1

    // stage 24 rows x 320 cols (coalesced; left-clip replication)
    for (int idx = t; idx < CO * 320; idx += 256) {
        const int c = idx / 320, Wd = idx % 320;
        const int col = colbase + Wd;
        frs[c * 324 + 2 + Wd] = fr[((size_t)(b * CO + c) * HQ + h) * WR + (col > 0 ? col : 0)];
    }
    __syncthreads();

    float accA[8], accB[8];
#pragma unroll
    for (int dd = 0; dd < 8; ++dd) { accA[dd] = 0.f; accB[dd] = 0.f; }

    for (int c = 0; c < CO; ++c) {
        const float2 flc = *(const float2*)&fl[((size_t)(b * CO + c) * HQ + h) * WL + j0 + cA];
        const float* base = &frs[c * 324 + 8 * p - 8 * g + 60];
        const float4 F0 = *(const float4*)(base);       // E[0..3]
        const float4 F1 = *(const float4*)(base + 4);   // E[4..7]
        const float4 F2 = *(const float4*)(base + 8);   // E[8..11]
        // col A: d = 8g+dd <- E[7-dd]
        accA[0] += fabsf(flc.x - F1.w);
        accA[1] += fabsf(flc.x - F1.z);
        accA[2] += fabsf(flc.x - F1.y);
        accA[3] += fabsf(flc.x - F1.x);
        accA[4] += fabsf(flc.x - F0.w);
        accA[5] += fabsf(flc.x - F0.z);
        accA[6] += fabsf(flc.x - F0.y);
        accA[7] += fabsf(flc.x - F0.x);
        // col B: d = 8g+dd <- E[11-dd]
        accB[0] += fabsf(flc.y - F2.w);
        accB[1] += fabsf(flc.y - F2.z);
        accB[2] += fabsf(flc.y - F2.y);
        accB[3] += fabsf(flc.y - F2.x);
        accB[4] += fabsf(flc.y - F1.w);
        accB[5] += fabsf(flc.y - F1.z);
        accB[6] += fabsf(flc.y - F1.y);
        accB[7] += fabsf(flc.y - F1.x);
    }

    // cost volume writes: 8 d-rows x float2 (cols 2p,2p+1) -- coalesced
#pragma unroll
    for (int dd = 0; dd < 8; ++dd) {
        const int d = 8 * g + dd;
        float2 st = make_float2(accA[dd], accB[dd]);
        *(float2*)&cost[((size_t)(b * DMAX + d) * HQ + h) * WL + j0 + cA] = st;
    }

    // per-thread per-col argmin over its 8 d's (ascending -> first occurrence)
    float bA = accA[0]; int dA = 8 * g;
    float bB = accB[0]; int dB = 8 * g;
#pragma unroll
    for (int dd = 1; dd < 8; ++dd) {
        if (accA[dd] < bA) { bA = accA[dd]; dA = 8 * g + dd; }
        if (accB[dd] < bB) { bB = accB[dd]; dB = 8 * g + dd; }
    }
    sbest[g * 64 + cA]     = bA; sbd[g * 64 + cA]     = dA;
    sbest[g * 64 + cA + 1] = bB; sbd[g * 64 + cA + 1] = dB;
    __syncthreads();

    // all 4 waves: reduce over g (ascending = global d-ascending), then each
    // wave computes its share of the 13 tf outputs (wave-uniform bounds).
    const int j = t & 63, w = t >> 6;
    const int jg = j0 + j;
    float cur = sbest[j]; int curd = sbd[j];
#pragma unroll
    for (int g2 = 1; g2 < 8; ++g2) {
        const float v = sbest[g2 * 64 + j];
        if (v < cur) { cur = v; curd = sbd[g2 * 64 + j]; }
    }
    float flr[CO];
#pragma unroll
    for (int c = 0; c < CO; ++c) flr[c] = fl[((size_t)(b * CO + c) * HQ + h) * WL + jg];

    const int o_lo = (w == 0) ? 0 : 4 * w - 3;   // 0,1,5,9
    const int o_hi = 4 * w + 1;                   // 1,5,9,13
    for (int o = o_lo; o < o_hi; ++o) {
        float a = btf[o] + wtf[o * 25] * cur;
#pragma unroll
        for (int c = 0; c < CO; ++c) a += wtf[o * 25 + 1 + c] * flr[c];
        out[((size_t)(b * 16 + 3 + o) * HQ + h) * WL + jg] = lk(a);
    }
    if (w == 0) {
        out[((size_t)(b * 16 + 0) * HQ + h) * WL + jg] = (float)curd;
        out[((size_t)(b * 16 + 1) * HQ + h) * WL + jg] = 0.f;
        out[((size_t)(b * 16 + 2) * HQ + h) * WL + jg] = 0.f;
    }
}

extern "C" void kernel_launch(void* const* d_in, const int* in_sizes, int n_in,
                              void* d_out, int out_size, void* d_ws, size_t ws_size,
                              hipStream_t stream) {
    const float* fl_in = (const float*)d_in[0];
    const float* fr_in = (const float*)d_in[1];
    // d_in[2] = max_disp (int) -- fixed 64
    const float* w_em = (const float*)d_in[3];
    const float* b_em = (const float*)d_in[4];
    const float* w_rc = (const float*)d_in[5];
    const float* b_rc = (const float*)d_in[6];
    const float* w_tf = (const float*)d_in[7];
    const float* b_tf = (const float*)d_in[8];

    float* out  = (float*)d_out;
    float* cost = out + (size_t)B_ * 16 * HQ * WL;

    float* fl_ws = (float*)d_ws;                               // [2,24,96,320]
    float* fr_ws = fl_ws + (size_t)B_ * CO * HQ * WL;          // [2,24,96,1280]

    hipLaunchKernelGGL(k_right, dim3(960), dim3(256), 0, stream,
                       fr_in, w_em, b_em, w_rc, b_rc, fr_ws);
    hipLaunchKernelGGL(k_left,  dim3(480), dim3(256), 0, stream,
                       fl_in, w_em, b_em, w_rc, b_rc, fl_ws);
    hipLaunchKernelGGL(k_cost,  dim3(960), dim3(256), 0, stream,
                       fl_ws, fr_ws, w_tf, b_tf, out, cost);
}

// Round 8
// 237.054 us; speedup vs baseline: 1.0883x; 1.0028x over previous
//
#include <hip/hip_runtime.h>

#define B_   2
#define CIN  16
#define HIN  384
#define WIN  1280
#define CO   24
#define HQ   96
#define WL   320
#define WR   1280
#define DMAX 64

__device__ __forceinline__ float lk(float v) { return v >= 0.f ? v : 0.2f * v; }

// ============ Fused embedding kernel: left + right branches =================
// R8: re-fuse on the LEAN bases (R2's fusion regression was the VGPR-160
// pipelined right branch, not fusion itself; both branches are now VGPR ~60).
// grid 1440: blockIdx%3==0 -> left (480), else right (960). Left's short
// blocks backfill right's latency stalls instead of 17us serial tail.
// Both branches share ONE LDS footprint (identical shapes): buf 6144 fl
// (weights, then acts), swt 576, biases -> 27136 B total, same as k_right.
// WATCH: VGPR must stay <=128 and WRITE_SIZE == 28800 (23040+5760), else
// the co-compiled branches spilled and fusion gets reverted.
__global__ __launch_bounds__(256) void k_em(
    const float* __restrict__ xl, const float* __restrict__ xr,
    const float* __restrict__ w_em, const float* __restrict__ b_em,
    const float* __restrict__ w_rc, const float* __restrict__ b_rc,
    float* __restrict__ out_l, float* __restrict__ out_r)
{
    __shared__ __align__(16) float buf[CO * CIN * 16];  // weights, then acts
    __shared__ __align__(16) float swt[CO * CO];        // rc weights [c][o]
    __shared__ float sbe[CO], sbr[CO];

    for (int i = threadIdx.x; i < CO * CIN * 16; i += 256) buf[i] = w_em[i];
    for (int i = threadIdx.x; i < CO * CO; i += 256) swt[i] = w_rc[(i % CO) * CO + (i / CO)];
    if (threadIdx.x < CO) { sbe[threadIdx.x] = b_em[threadIdx.x]; sbr[threadIdx.x] = b_rc[threadIdx.x]; }
    __syncthreads();

    const int t = threadIdx.x;

    if (blockIdx.x % 3 == 0) {
        // ---------------- LEFT branch (4x4 s4,4 VALID) -- exact R0 body ------
        const int lb = blockIdx.x / 3;
        const int half = t >> 7, pxl = t & 127;
        const int obase = half * 12;
        const int flat = lb * 128 + pxl;              // < 61440
        const int j = flat % WL, h = (flat / WL) % HQ, b = flat / (WL * HQ);

        float acc[12];
#pragma unroll
        for (int oo = 0; oo < 12; ++oo) acc[oo] = sbe[obase + oo];

        for (int c = 0; c < CIN; ++c) {
#pragma unroll
            for (int kh = 0; kh < 4; ++kh) {
                const float4 v = *(const float4*)(xl + ((size_t)(b * CIN + c) * HIN + 4 * h + kh) * WIN + 4 * j);
#pragma unroll
                for (int oo = 0; oo < 12; ++oo) {
                    const float4 wv = *(const float4*)&buf[(((obase + oo) * CIN + c) * 4 + kh) * 4];
                    acc[oo] += v.x * wv.x + v.y * wv.y + v.z * wv.z + v.w * wv.w;
                }
            }
        }
        __syncthreads();
#pragma unroll
        for (int oo = 0; oo < 12; ++oo) buf[(obase + oo) * 128 + pxl] = lk(acc[oo]);
        __syncthreads();

        float acc2[12];
#pragma unroll
        for (int oo = 0; oo < 12; ++oo) acc2[oo] = sbr[obase + oo];
        for (int c = 0; c < CO; ++c) {
            const float in_c = buf[c * 128 + pxl];
#pragma unroll
            for (int oo = 0; oo < 12; ++oo) acc2[oo] += in_c * swt[c * CO + obase + oo];
        }
#pragma unroll
        for (int oo = 0; oo < 12; ++oo)
            out_l[((size_t)(b * CO + obase + oo) * HQ + h) * WL + j] = lk(acc2[oo]);
    } else {
        // ---------------- RIGHT branch (4x4 s4,1 pad 1,2) -- exact R5 body ---
        const int rb = blockIdx.x - blockIdx.x / 3 - 1;   // bijective -> [0,960)
        const int L = t & 63, quarter = t >> 6;
        const int obase = quarter * 6;
        const int row = rb / 5, jbase = (rb % 5) * 256;
        const int b = row / HQ, h = row % HQ;

        const bool vm1 = (jbase + 4 * L) > 0;
        const bool vp  = (jbase + 4 * L + 4) < WIN;
        const int  om1 = vm1 ? (4 * L - 2) : 0;
        const int  op4 = vp  ? (4 * L + 4) : 0;

        float acc[4][6];
#pragma unroll
        for (int k = 0; k < 4; ++k)
#pragma unroll
            for (int oo = 0; oo < 6; ++oo) acc[k][oo] = sbe[obase + oo];

        for (int c = 0; c < CIN; ++c) {
#pragma unroll
            for (int kh = 0; kh < 4; ++kh) {
                const float* xp = xr + ((size_t)(b * CIN + c) * HIN + 4 * h + kh) * WIN + jbase;
                const float4  v = *(const float4*)(xp + 4 * L);
                const float2  A = *(const float2*)(xp + om1);   // cols 4L-2, 4L-1
                const float2  C = *(const float2*)(xp + op4);   // cols 4L+4, 4L+5
                float in[7];
                in[0] = vm1 ? A.y : 0.f;
                in[1] = v.x; in[2] = v.y; in[3] = v.z; in[4] = v.w;
                in[5] = vp ? C.x : 0.f;
                in[6] = vp ? C.y : 0.f;
#pragma unroll
                for (int oo = 0; oo < 6; ++oo) {
                    const float4 wv = *(const float4*)&buf[(((obase + oo) * CIN + c) * 4 + kh) * 4];
#pragma unroll
                    for (int k = 0; k < 4; ++k) {
                        float a = acc[k][oo];
                        a = fmaf(in[k],     wv.x, a);
                        a = fmaf(in[k + 1], wv.y, a);
                        a = fmaf(in[k + 2], wv.z, a);
                        a = fmaf(in[k + 3], wv.w, a);
                        acc[k][oo] = a;
                    }
                }
            }
        }
        __syncthreads();   // done reading em weights; buf becomes act buffer [24][256]
#pragma unroll
        for (int oo = 0; oo < 6; ++oo) {
            float4 st = make_float4(lk(acc[0][oo]), lk(acc[1][oo]), lk(acc[2][oo]), lk(acc[3][oo]));
            *(float4*)&buf[(obase + oo) * 256 + 4 * L] = st;
        }
        __syncthreads();

        float acc2[CO];
#pragma unroll
        for (int o = 0; o < CO; ++o) acc2[o] = sbr[o];
        for (int c = 0; c < CO; ++c) {
            const float in_c = buf[c * 256 + t];
#pragma unroll
            for (int m = 0; m < 6; ++m) {
                const float4 wv = *(const float4*)&swt[c * CO + 4 * m];   // 16B aligned
                acc2[4 * m + 0] = fmaf(in_c, wv.x, acc2[4 * m + 0]);
                acc2[4 * m + 1] = fmaf(in_c, wv.y, acc2[4 * m + 1]);
                acc2[4 * m + 2] = fmaf(in_c, wv.z, acc2[4 * m + 2]);
                acc2[4 * m + 3] = fmaf(in_c, wv.w, acc2[4 * m + 3]);
            }
        }
#pragma unroll
        for (int o = 0; o < CO; ++o)
            out_r[((size_t)(b * CO + o) * HQ + h) * WR + jbase + t] = lk(acc2[o]);
    }
}

// ====== Kernel C: cost volume + min/argmin + tf 1x1 + output assembly ========
// R8: HYBRID = R6's conflict-free gather (lane stride 16B contiguous; R7's
// col-paired 32B-stride gather was a ~8-way bank conflict -- 3 conflicted
// reads/c cost more LDS cycles than 4 clean ones) + R7's parallel tail
// (the actual R7 win: tf 1x1 split across all 4 waves; the g-reduction is
// same-address across waves -> LDS broadcast, free).
// block 256 = 64 j-lanes x 4 waves (wave w owns d in [16w,16w+16)); grid 960.
// Channel-ascending += of fabsf keeps costs bitwise-identical.
__global__ __launch_bounds__(256) void k_cost(
    const float* __restrict__ fl, const float* __restrict__ fr,
    const float* __restrict__ wtf, const float* __restrict__ btf,
    float* __restrict__ out, float* __restrict__ cost)
{
    __shared__ float frs[CO * 324];       // 31104 B
    __shared__ float sbest[256];
    __shared__ int   sbd[256];

    const int t  = threadIdx.x;
    const int j  = t & 63;                 // lane = local col
    const int w  = t >> 6;                 // wave: d in [16w, 16w+16)
    const int jc = blockIdx.x % 5;
    const int r  = blockIdx.x / 5;
    const int h  = r % HQ, b = r / HQ;
    const int j0 = jc * 64;
    const int jg = j0 + j;
    const int colbase = 4 * j0 - 64;

    // stage 24 rows x 320 cols (coalesced; left-clip replication)
    for (int idx = t; idx < CO * 320; idx += 256) {
        const int c = idx / 320, Wd = idx % 320;
        const int col = colbase + Wd;
        frs[c * 324 + 2 + Wd] = fr[((size_t)(b * CO + c) * HQ + h) * WR + (col > 0 ? col : 0)];
    }
    __syncthreads();

    float acc[4][4];                       // [q][r], d = 16w + 4q + r
#pragma unroll
    for (int q = 0; q < 4; ++q)
#pragma unroll
        for (int rr = 0; rr < 4; ++rr) acc[q][rr] = 0.f;

    for (int c = 0; c < CO; ++c) {
        const float flc = fl[((size_t)(b * CO + c) * HQ + h) * WL + jg];
        const float* base = &frs[c * 324 + 4 * j + 64];
#pragma unroll
        for (int q = 0; q < 4; ++q) {
            const int D = 4 * w + q;
            const float4 v = *(const float4*)(base - 4 * D);  // 16B-aligned, lanes contiguous
            acc[q][0] += fabsf(flc - v.w);   // d = 4D
            acc[q][1] += fabsf(flc - v.z);   // d = 4D+1
            acc[q][2] += fabsf(flc - v.y);   // d = 4D+2
            acc[q][3] += fabsf(flc - v.x);   // d = 4D+3
        }
    }

    // cost volume writes (coalesced over jg)
#pragma unroll
    for (int q = 0; q < 4; ++q)
#pragma unroll
        for (int rr = 0; rr < 4; ++rr) {
            const int d = 16 * w + 4 * q + rr;
            cost[((size_t)(b * DMAX + d) * HQ + h) * WL + jg] = acc[q][rr];
        }

    // per-thread min / first-occurrence argmin (ascending d within wave range)
    float best = acc[0][0]; int bd = 16 * w;
#pragma unroll
    for (int q = 0; q < 4; ++q)
#pragma unroll
        for (int rr = 0; rr < 4; ++rr) {
            if (q == 0 && rr == 0) continue;
            const int d = 16 * w + 4 * q + rr;
            if (acc[q][rr] < best) { best = acc[q][rr]; bd = d; }
        }
    sbest[t] = best; sbd[t] = bd;
    __syncthreads();

    // all 4 waves: g-ascending reduce (same addrs across waves -> broadcast),
    // then each wave computes its share of the 13 tf outputs.
    float cur = sbest[j]; int curd = sbd[j];
#pragma unroll
    for (int g = 1; g < 4; ++g) {
        const float v = sbest[g * 64 + j];
        if (v < cur) { cur = v; curd = sbd[g * 64 + j]; }
    }
    float flr[CO];
#pragma unroll
    for (int c = 0; c < CO; ++c) flr[c] = fl[((size_t)(b * CO + c) * HQ + h) * WL + jg];

    const int o_lo = (w == 0) ? 0 : 4 * w - 3;   // 0,1,5,9
    const int o_hi = 4 * w + 1;                   // 1,5,9,13
    for (int o = o_lo; o < o_hi; ++o) {
        float a = btf[o] + wtf[o * 25] * cur;
#pragma unroll
        for (int c = 0; c < CO; ++c) a += wtf[o * 25 + 1 + c] * flr[c];
        out[((size_t)(b * 16 + 3 + o) * HQ + h) * WL + jg] = lk(a);
    }
    if (w == 0) {
        out[((size_t)(b * 16 + 0) * HQ + h) * WL + jg] = (float)curd;
        out[((size_t)(b * 16 + 1) * HQ + h) * WL + jg] = 0.f;
        out[((size_t)(b * 16 + 2) * HQ + h) * WL + jg] = 0.f;
    }
}

extern "C" void kernel_launch(void* const* d_in, const int* in_sizes, int n_in,
                              void* d_out, int out_size, void* d_ws, size_t ws_size,
                              hipStream_t stream) {
    const float* fl_in = (const float*)d_in[0];
    const float* fr_in = (const float*)d_in[1];
    // d_in[2] = max_disp (int) -- fixed 64
    const float* w_em = (const float*)d_in[3];
    const float* b_em = (const float*)d_in[4];
    const float* w_rc = (const float*)d_in[5];
    const float* b_rc = (const float*)d_in[6];
    const float* w_tf = (const float*)d_in[7];
    const float* b_tf = (const float*)d_in[8];

    float* out  = (float*)d_out;
    float* cost = out + (size_t)B_ * 16 * HQ * WL;

    float* fl_ws = (float*)d_ws;                               // [2,24,96,320]
    float* fr_ws = fl_ws + (size_t)B_ * CO * HQ * WL;          // [2,24,96,1280]

    hipLaunchKernelGGL(k_em, dim3(1440), dim3(256), 0, stream,
                       fl_in, fr_in, w_em, b_em, w_rc, b_rc, fl_ws, fr_ws);
    hipLaunchKernelGGL(k_cost, dim3(960), dim3(256), 0, stream,
                       fl_ws, fr_ws, w_tf, b_tf, out, cost);
}